// Round 6
// baseline (414.289 us; speedup 1.0000x reference)
//
#include <hip/hip_runtime.h>
#include <stdint.h>

#define DEVINL __device__ __forceinline__

typedef short bf16x8 __attribute__((ext_vector_type(8)));
typedef float f32x4  __attribute__((ext_vector_type(4)));

// ---------- bf16 helpers (RNE) ----------
DEVINL uint16_t f2bf(float f) {
    uint32_t u = __builtin_bit_cast(uint32_t, f);
    uint32_t r = u + 0x7fffu + ((u >> 16) & 1u);
    return (uint16_t)(r >> 16);
}

DEVINL f32x4 mfma16x16x32(bf16x8 a, bf16x8 b, f32x4 c) {
    return __builtin_amdgcn_mfma_f32_16x16x32_bf16(a, b, c, 0, 0, 0);
}

// pack 8 f32 -> bf16x8
DEVINL bf16x8 pack8(float4 v0, float4 v1) {
    union { bf16x8 v; uint16_t us[8]; } pk;
    pk.us[0] = f2bf(v0.x); pk.us[1] = f2bf(v0.y);
    pk.us[2] = f2bf(v0.z); pk.us[3] = f2bf(v0.w);
    pk.us[4] = f2bf(v1.x); pk.us[5] = f2bf(v1.y);
    pk.us[6] = f2bf(v1.z); pk.us[7] = f2bf(v1.w);
    return pk.v;
}

// ---------- ws layout (bytes) ----------
// We1T bf16 [256][800] @ 0       size 409600  (cols 784..799 zero)
// We2T bf16 [32][256]  @ 409600  size 16384
// W1T  bf16 [128][32]  @ 425984  size 8192
// W2T  bf16 [16][128]  @ 434176  size 4096    (cols 10..15 zero)
#define WS_WE1T 0
#define WS_WE2T 409600
#define WS_W1T  425984
#define WS_W2T  434176

// ================= prep: transpose + f32->bf16 weights =================
__global__ __launch_bounds__(256) void prep_weights(
    const float* __restrict__ We1, const float* __restrict__ We2,
    const float* __restrict__ W1,  const float* __restrict__ W2,
    uint16_t* __restrict__ We1T, uint16_t* __restrict__ We2T,
    uint16_t* __restrict__ W1T,  uint16_t* __restrict__ W2T) {
    int tid = blockIdx.x * 256 + threadIdx.x;
    if (tid < 256 * 800) {                   // We1T[n][k] = We1[k][n], k-pad to 800
        int n = tid / 800, k = tid % 800;
        We1T[tid] = (k < 784) ? f2bf(We1[k * 256 + n]) : (uint16_t)0;
        return;
    }
    int t2 = tid - 256 * 800;
    if (t2 < 32 * 256) {                     // We2T[n][k] = We2[k][n]
        int n = t2 / 256, k = t2 % 256;
        We2T[t2] = f2bf(We2[k * 32 + n]);
        return;
    }
    int t3 = t2 - 32 * 256;
    if (t3 < 128 * 32) {                     // W1T[n][k] = W1[k][n]
        int n = t3 / 32, k = t3 % 32;
        W1T[t3] = f2bf(W1[k * 128 + n]);
        return;
    }
    int t4 = t3 - 128 * 32;
    if (t4 < 16 * 128) {                     // W2T[n][k] = W2[k][n], pad n>=10 with 0
        int n = t4 / 128, k = t4 % 128;
        W2T[t4] = (n < 10) ? f2bf(W2[k * 10 + n]) : (uint16_t)0;
        return;
    }
}

// ================= quantum circuit (fixed angles, fully unrolled) =================
DEVINL void apply_rx(float* sr, float* si, int bit, float c, float s) {
    #pragma unroll
    for (int i = 0; i < 16; i++) {
        if (!(i & bit)) {
            int j = i | bit;
            float r0 = sr[i], i0 = si[i], r1 = sr[j], i1 = si[j];
            sr[i] = c * r0 + s * i1;  si[i] = c * i0 - s * r1;
            sr[j] = c * r1 + s * i0;  si[j] = c * i1 - s * r0;
        }
    }
}
DEVINL void apply_ry(float* sr, float* si, int bit, float c, float s) {
    #pragma unroll
    for (int i = 0; i < 16; i++) {
        if (!(i & bit)) {
            int j = i | bit;
            float r0 = sr[i], i0 = si[i], r1 = sr[j], i1 = si[j];
            sr[i] = c * r0 - s * r1;  si[i] = c * i0 - s * i1;
            sr[j] = s * r0 + c * r1;  si[j] = s * i0 + c * i1;
        }
    }
}
DEVINL void apply_cnot(float* sr, float* si, int cb, int tb) {
    #pragma unroll
    for (int i = 0; i < 16; i++) {
        if ((i & cb) && !(i & tb)) {
            int j = i | tb;
            float tr = sr[i]; sr[i] = sr[j]; sr[j] = tr;
            float ti = si[i]; si[i] = si[j]; si[j] = ti;
        }
    }
}
DEVINL void circuit(float* sr, float* si) {
    const float C1 = 0.99875026039496628f, S1 = 0.04997916927067833f;  // rx(0.1)
    const float C2 = 0.99500416527802582f, S2 = 0.09983341664682815f;  // ry(0.2)
    const float C3 = 0.98877107793604227f, S3 = 0.14943813247359922f;  // rx(0.3)
    const float C4 = 0.98006657784124163f, S4 = 0.19866933079506122f;  // ry(0.4)
    #pragma unroll
    for (int q = 0; q < 4; q++) {
        int bit = 8 >> q;
        apply_rx(sr, si, bit, C1, S1);
        apply_ry(sr, si, bit, C2, S2);
    }
    apply_cnot(sr, si, 8, 4);
    apply_cnot(sr, si, 4, 2);
    apply_cnot(sr, si, 2, 1);
    #pragma unroll
    for (int q = 0; q < 4; q++) {
        int bit = 8 >> q;
        apply_rx(sr, si, bit, C3, S3);
        apply_ry(sr, si, bit, C4, S4);
    }
}

// ================= fused: GEMM1+relu + GEMM2+tanh + norm+circuit + classifier =================
// 2048 blocks x 256 thr (4 waves); 32 rows/block; wave tile 32x64.
// K-loop: ZERO barriers, ZERO LDS. A frags direct from global x (MFMA-layout
// reads: 16 rows x 128 B lines), f32->bf16 in-register, 1-deep pipeline.
// B frags direct from L2-hot We1T. acc = 32 regs -> ~100 unified regs ->
// 5 waves/SIMD (launch_bounds(256,5)) = 20 waves/CU.
// LDS 17408-B arena used only in the tail (Htile -> enc/feat/a1).
__global__ __launch_bounds__(256, 5) void fused_kernel(
    const float* __restrict__ x, const uint16_t* __restrict__ We1T,
    const float* __restrict__ be1,
    const uint16_t* __restrict__ We2T, const float* __restrict__ be2,
    const uint16_t* __restrict__ W1T, const float* __restrict__ b1,
    const uint16_t* __restrict__ W2T, const float* __restrict__ b2,
    float* __restrict__ out) {
    __shared__ __align__(16) char smem[17408];
    uint16_t* Htile  = (uint16_t*)smem;            // [32][272] bf16 = 17408 B
    float*    encls  = (float*)smem;               // [32][33] f32 = 4224 B
    uint16_t* featls = (uint16_t*)(smem + 4224);   // [32][40] bf16 = 2560 B
    uint16_t* a1ls   = (uint16_t*)(smem + 6784);   // [32][136] bf16 = 8704 B

    const int t = threadIdx.x;
    const int rowbase = blockIdx.x * 32;
    const int w  = t >> 6;     // wave 0..3 -> col-block w*64 in GEMM1
    const int l  = t & 63;
    const int lm = l & 15;
    const int lq = l >> 4;

    f32x4 acc[2][4] = {};      // [mi][ni]: rows mi*16.., cols w*64+ni*16..

    // A: lane reads x[rowbase + mi*16 + lm][k0 + lq*8 .. +7] (two float4)
    const float* arow0 = x + (size_t)(rowbase + lm) * 784 + lq * 8;
    const float* arow1 = arow0 + 16 * 784;
    // B: lane reads We1T[w*64 + ni*16 + lm][k0 + lq*8 .. +7]
    const uint16_t* bbase = We1T + (size_t)(w * 64 + lm) * 800 + lq * 8;

    // ---- prologue: load A(k0=0); c = lq*8 <= 24 < 784 always valid ----
    float4 a00 = *(const float4*)(arow0);
    float4 a01 = *(const float4*)(arow0 + 4);
    float4 a10 = *(const float4*)(arow1);
    float4 a11 = *(const float4*)(arow1 + 4);

    for (int k0 = 0; k0 < 800; k0 += 32) {
        // ---- issue next-iter A loads (guarded; c multiple of 8, need c<784) ----
        float4 n00, n01, n10, n11;
        int kn = k0 + 32;
        if (kn < 800) {
            int c = kn + lq * 8;
            if (c < 784) {
                n00 = *(const float4*)(arow0 + kn);
                n01 = *(const float4*)(arow0 + kn + 4);
                n10 = *(const float4*)(arow1 + kn);
                n11 = *(const float4*)(arow1 + kn + 4);
            } else {
                n00 = n01 = n10 = n11 = make_float4(0.f, 0.f, 0.f, 0.f);
            }
        } else {
            n00 = n01 = n10 = n11 = make_float4(0.f, 0.f, 0.f, 0.f);
        }

        // ---- B frags for current k0 (direct from L2-hot We1T) ----
        bf16x8 bfr[4];
        #pragma unroll
        for (int ni = 0; ni < 4; ni++)
            bfr[ni] = *(const bf16x8*)(bbase + (size_t)(ni * 16) * 800 + k0);

        // ---- convert current A -> frags ----
        bf16x8 afr0 = pack8(a00, a01);
        bf16x8 afr1 = pack8(a10, a11);

        // ---- MFMA ----
        #pragma unroll
        for (int ni = 0; ni < 4; ni++) {
            acc[0][ni] = mfma16x16x32(afr0, bfr[ni], acc[0][ni]);
            acc[1][ni] = mfma16x16x32(afr1, bfr[ni], acc[1][ni]);
        }

        // ---- rotate ----
        a00 = n00; a01 = n01; a10 = n10; a11 = n11;
    }

    // ---- GEMM1 epilogue: relu(+bias) -> Htile bf16 [32][272] ----
    #pragma unroll
    for (int ni = 0; ni < 4; ni++) {
        int n = w * 64 + ni * 16 + lm;
        float bias = be1[n];
        #pragma unroll
        for (int mi = 0; mi < 2; mi++) {
            #pragma unroll
            for (int i = 0; i < 4; i++) {
                int r = mi * 16 + lq * 4 + i;
                float v = acc[mi][ni][i] + bias;
                v = v > 0.f ? v : 0.f;
                Htile[r * 272 + n] = f2bf(v);
            }
        }
    }
    __syncthreads();   // Htile complete

    // ---- GEMM2: enc_pre = h @ We2, K=256. wave w -> rows (w&1)*16, cols (w>>1)*16 ----
    const int mrow = (w & 1) * 16;
    const int ncol = (w >> 1) * 16;
    f32x4 acc2 = {};
    #pragma unroll
    for (int k0 = 0; k0 < 256; k0 += 32) {
        bf16x8 af = *(const bf16x8*)&Htile[(mrow + lm) * 272 + k0 + lq * 8];
        bf16x8 bf = *(const bf16x8*)&We2T[(ncol + lm) * 256 + k0 + lq * 8];
        acc2 = mfma16x16x32(af, bf, acc2);
    }
    __syncthreads();   // all Htile reads done; arena becomes enc/feat/a1

    // ---- enc = tanh(acc + be2) -> LDS ----
    {
        int col = ncol + lm;
        float bias = be2[col];
        #pragma unroll
        for (int i = 0; i < 4; i++) {
            int r = mrow + lq * 4 + i;
            encls[r * 33 + col] = tanhf(acc2[i] + bias);
        }
    }
    __syncthreads();   // enc visible cross-wave

    // ---- per-row: normalize + quantum circuit -> feat bf16 ----
    if (t < 32) {
        float e[32];
        #pragma unroll
        for (int j = 0; j < 32; j++) e[j] = encls[t * 33 + j];
        float s = 0.f;
        #pragma unroll
        for (int j = 0; j < 32; j++) s += e[j] * e[j];
        float inv = 1.0f / sqrtf(s);
        float sr[16], si[16];
        #pragma unroll
        for (int i = 0; i < 16; i++) { sr[i] = e[i] * inv; si[i] = e[16 + i] * inv; }
        circuit(sr, si);
        #pragma unroll
        for (int i = 0; i < 16; i++) {
            featls[t * 40 + i]      = f2bf(sr[i]);
            featls[t * 40 + 16 + i] = f2bf(si[i]);
        }
    }
    __syncthreads();   // feat visible cross-wave

    // ---- classifier L1: a1 = relu(feat @ W1 + b1), K=32. wave w -> rows (w&1)*16, cols (w>>1)*64 ----
    const int nc64 = (w >> 1) * 64;
    f32x4 acc3[4] = {};
    {
        bf16x8 af = *(const bf16x8*)&featls[(mrow + lm) * 40 + lq * 8];
        #pragma unroll
        for (int ni = 0; ni < 4; ni++) {
            bf16x8 bf = *(const bf16x8*)&W1T[(nc64 + ni * 16 + lm) * 32 + lq * 8];
            acc3[ni] = mfma16x16x32(af, bf, acc3[ni]);
        }
    }
    #pragma unroll
    for (int ni = 0; ni < 4; ni++) {
        int col = nc64 + ni * 16 + lm;
        float bias = b1[col];
        #pragma unroll
        for (int i = 0; i < 4; i++) {
            int r = mrow + lq * 4 + i;
            float v = acc3[ni][i] + bias;
            v = v > 0.f ? v : 0.f;
            a1ls[r * 136 + col] = f2bf(v);
        }
    }
    __syncthreads();   // cross-wave: L2 reads cols written by other waves

    // ---- classifier L2: out = a1 @ W2 + b2, K=128, N=16 (10 real). waves 0,1 only ----
    if (w < 2) {
        f32x4 acc4 = {};
        #pragma unroll
        for (int k0 = 0; k0 < 128; k0 += 32) {
            bf16x8 af = *(const bf16x8*)&a1ls[(w * 16 + lm) * 136 + k0 + lq * 8];
            bf16x8 bf = *(const bf16x8*)&W2T[lm * 128 + k0 + lq * 8];
            acc4 = mfma16x16x32(af, bf, acc4);
        }
        if (lm < 10) {
            float bias = b2[lm];
            #pragma unroll
            for (int i = 0; i < 4; i++) {
                int r = rowbase + w * 16 + lq * 4 + i;
                out[(size_t)r * 10 + lm] = acc4[i] + bias;
            }
        }
    }
}

extern "C" void kernel_launch(void* const* d_in, const int* in_sizes, int n_in,
                              void* d_out, int out_size, void* d_ws, size_t ws_size,
                              hipStream_t stream) {
    const float* x   = (const float*)d_in[0];
    const float* We1 = (const float*)d_in[1];
    const float* be1 = (const float*)d_in[2];
    const float* We2 = (const float*)d_in[3];
    const float* be2 = (const float*)d_in[4];
    const float* W1  = (const float*)d_in[5];
    const float* b1  = (const float*)d_in[6];
    const float* W2  = (const float*)d_in[7];
    const float* b2  = (const float*)d_in[8];
    float* out = (float*)d_out;

    char* ws = (char*)d_ws;
    uint16_t* We1T = (uint16_t*)(ws + WS_WE1T);
    uint16_t* We2T = (uint16_t*)(ws + WS_WE2T);
    uint16_t* W1T  = (uint16_t*)(ws + WS_W1T);
    uint16_t* W2T  = (uint16_t*)(ws + WS_W2T);

    hipLaunchKernelGGL(prep_weights, dim3(856), dim3(256), 0, stream,
                       We1, We2, W1, W2, We1T, We2T, W1T, W2T);
    hipLaunchKernelGGL(fused_kernel, dim3(2048), dim3(256), 0, stream,
                       x, We1T, be1, We2T, be2, W1T, b1, W2T, b2, out);
}

// Round 7
// 379.259 us; speedup vs baseline: 1.0924x; 1.0924x over previous
//
#include <hip/hip_runtime.h>
#include <stdint.h>

#define DEVINL __device__ __forceinline__

typedef short bf16x8 __attribute__((ext_vector_type(8)));
typedef float f32x4  __attribute__((ext_vector_type(4)));

// ---------- bf16 helpers (RNE) ----------
DEVINL uint16_t f2bf(float f) {
    uint32_t u = __builtin_bit_cast(uint32_t, f);
    uint32_t r = u + 0x7fffu + ((u >> 16) & 1u);
    return (uint16_t)(r >> 16);
}

DEVINL f32x4 mfma16x16x32(bf16x8 a, bf16x8 b, f32x4 c) {
    return __builtin_amdgcn_mfma_f32_16x16x32_bf16(a, b, c, 0, 0, 0);
}

// pack 8 f32 -> bf16x8
DEVINL bf16x8 pack8(float4 v0, float4 v1) {
    union { bf16x8 v; uint16_t us[8]; } pk;
    pk.us[0] = f2bf(v0.x); pk.us[1] = f2bf(v0.y);
    pk.us[2] = f2bf(v0.z); pk.us[3] = f2bf(v0.w);
    pk.us[4] = f2bf(v1.x); pk.us[5] = f2bf(v1.y);
    pk.us[6] = f2bf(v1.z); pk.us[7] = f2bf(v1.w);
    return pk.v;
}

// raw barrier: drain ONLY LDS ops (global loads stay in flight)
DEVINL void lds_barrier() {
    asm volatile("s_waitcnt lgkmcnt(0)\n\ts_barrier" ::: "memory");
}

// ---------- ws layout (bytes) ----------
// We1T bf16 [256][832] @ 0       size 425984  (cols 784..831 zero)
// We2T bf16 [32][256]  @ 425984  size 16384
// W1T  bf16 [128][32]  @ 442368  size 8192
// W2T  bf16 [16][128]  @ 450560  size 4096    (cols 10..15 zero)
#define WS_WE1T 0
#define WS_WE2T 425984
#define WS_W1T  442368
#define WS_W2T  450560

// ================= prep: transpose + f32->bf16 weights =================
__global__ __launch_bounds__(256) void prep_weights(
    const float* __restrict__ We1, const float* __restrict__ We2,
    const float* __restrict__ W1,  const float* __restrict__ W2,
    uint16_t* __restrict__ We1T, uint16_t* __restrict__ We2T,
    uint16_t* __restrict__ W1T,  uint16_t* __restrict__ W2T) {
    int tid = blockIdx.x * 256 + threadIdx.x;
    if (tid < 256 * 832) {                   // We1T[n][k] = We1[k][n], k-pad to 832
        int n = tid / 832, k = tid % 832;
        We1T[tid] = (k < 784) ? f2bf(We1[k * 256 + n]) : (uint16_t)0;
        return;
    }
    int t2 = tid - 256 * 832;
    if (t2 < 32 * 256) {                     // We2T[n][k] = We2[k][n]
        int n = t2 / 256, k = t2 % 256;
        We2T[t2] = f2bf(We2[k * 32 + n]);
        return;
    }
    int t3 = t2 - 32 * 256;
    if (t3 < 128 * 32) {                     // W1T[n][k] = W1[k][n]
        int n = t3 / 32, k = t3 % 32;
        W1T[t3] = f2bf(W1[k * 128 + n]);
        return;
    }
    int t4 = t3 - 128 * 32;
    if (t4 < 16 * 128) {                     // W2T[n][k] = W2[k][n], pad n>=10 with 0
        int n = t4 / 128, k = t4 % 128;
        W2T[t4] = (n < 10) ? f2bf(W2[k * 10 + n]) : (uint16_t)0;
        return;
    }
}

// ================= quantum circuit (fixed angles, fully unrolled) =================
DEVINL void apply_rx(float* sr, float* si, int bit, float c, float s) {
    #pragma unroll
    for (int i = 0; i < 16; i++) {
        if (!(i & bit)) {
            int j = i | bit;
            float r0 = sr[i], i0 = si[i], r1 = sr[j], i1 = si[j];
            sr[i] = c * r0 + s * i1;  si[i] = c * i0 - s * r1;
            sr[j] = c * r1 + s * i0;  si[j] = c * i1 - s * r0;
        }
    }
}
DEVINL void apply_ry(float* sr, float* si, int bit, float c, float s) {
    #pragma unroll
    for (int i = 0; i < 16; i++) {
        if (!(i & bit)) {
            int j = i | bit;
            float r0 = sr[i], i0 = si[i], r1 = sr[j], i1 = si[j];
            sr[i] = c * r0 - s * r1;  si[i] = c * i0 - s * i1;
            sr[j] = s * r0 + c * r1;  si[j] = s * i0 + c * i1;
        }
    }
}
DEVINL void apply_cnot(float* sr, float* si, int cb, int tb) {
    #pragma unroll
    for (int i = 0; i < 16; i++) {
        if ((i & cb) && !(i & tb)) {
            int j = i | tb;
            float tr = sr[i]; sr[i] = sr[j]; sr[j] = tr;
            float ti = si[i]; si[i] = si[j]; si[j] = ti;
        }
    }
}
DEVINL void circuit(float* sr, float* si) {
    const float C1 = 0.99875026039496628f, S1 = 0.04997916927067833f;  // rx(0.1)
    const float C2 = 0.99500416527802582f, S2 = 0.09983341664682815f;  // ry(0.2)
    const float C3 = 0.98877107793604227f, S3 = 0.14943813247359922f;  // rx(0.3)
    const float C4 = 0.98006657784124163f, S4 = 0.19866933079506122f;  // ry(0.4)
    #pragma unroll
    for (int q = 0; q < 4; q++) {
        int bit = 8 >> q;
        apply_rx(sr, si, bit, C1, S1);
        apply_ry(sr, si, bit, C2, S2);
    }
    apply_cnot(sr, si, 8, 4);
    apply_cnot(sr, si, 4, 2);
    apply_cnot(sr, si, 2, 1);
    #pragma unroll
    for (int q = 0; q < 4; q++) {
        int bit = 8 >> q;
        apply_rx(sr, si, bit, C3, S3);
        apply_ry(sr, si, bit, C4, S4);
    }
}

// ================= fused: GEMM1+relu + GEMM2+tanh + norm+circuit + classifier =================
// 2048 blocks x 256 thr (4 waves); 32 rows/block; wave tile 32x64; BK=64.
// A: staged ONCE per block through LDS double-buffer ([2][32][72] bf16, stride-72
//    padding -> bank-uniform b128 writes AND frag reads), 1-deep register
//    prefetch (covers a full ~600-cyc iteration).
// B: direct from L2-hot We1T (wave-private columns, zero sharing).
// Barriers: 14 lgkm-only per block (no vmcnt drains). 16 MFMA per iter per wave.
// Regs ~105 -> 4 waves/SIMD at launch_bounds(256,4); LDS 17408 B.
__global__ __launch_bounds__(256, 4) void fused_kernel(
    const float* __restrict__ x, const uint16_t* __restrict__ We1T,
    const float* __restrict__ be1,
    const uint16_t* __restrict__ We2T, const float* __restrict__ be2,
    const uint16_t* __restrict__ W1T, const float* __restrict__ b1,
    const uint16_t* __restrict__ W2T, const float* __restrict__ b2,
    float* __restrict__ out) {
    __shared__ __align__(16) char smem[17408];
    // phase 1 (K-loop): A dbuf [2][32][72] bf16 = 9216 B
    uint16_t* Als = (uint16_t*)smem;
    // phase 2: Htile [32][272] bf16 = 17408 B (whole arena)
    uint16_t* Htile = (uint16_t*)smem;
    // phase 3 (tail): enc/feat/a1
    float*    encls  = (float*)smem;               // [32][33] f32 = 4224 B
    uint16_t* featls = (uint16_t*)(smem + 4224);   // [32][40] bf16 = 2560 B
    uint16_t* a1ls   = (uint16_t*)(smem + 6784);   // [32][136] bf16 = 8704 B

    const int t = threadIdx.x;
    const int rowbase = blockIdx.x * 32;
    const int w  = t >> 6;     // wave 0..3 -> col-block w*64 in GEMM1
    const int l  = t & 63;
    const int lm = l & 15;
    const int lq = l >> 4;

    f32x4 acc[2][4] = {};      // [mi][ni]: rows mi*16.., cols w*64+ni*16..

    // A staging: thread t -> row t>>3 (0..31), cols (t&7)*8..+7 within 64-wide tile
    const int sr_ = t >> 3;
    const int sc_ = (t & 7) * 8;
    const float* xrow = x + (size_t)(rowbase + sr_) * 784 + sc_;
    const int swaddr = sr_ * 72 + sc_;            // elem offset in slot (slot = 2304 elems)

    // B frag base (direct-global, wave-private cols)
    const uint16_t* bbase = We1T + (size_t)(w * 64 + lm) * 832 + lq * 8;

    // ---- prologue: stage tile0 (k=0..63) -> slot0; load tile1 regs ----
    {
        float4 p0 = *(const float4*)(xrow);       // sc_ <= 56 < 784
        float4 p1 = *(const float4*)(xrow + 4);
        *(bf16x8*)&Als[swaddr] = pack8(p0, p1);
    }
    float4 q0 = *(const float4*)(xrow + 64);      // 64+sc_ <= 120 < 784
    float4 q1 = *(const float4*)(xrow + 68);
    lds_barrier();

    int buf = 0;
    for (int it = 0; it < 13; ++it) {
        const int k0 = it * 64;

        // ---- B frags for current tile (8 x 16B loads; compiler vmcnt-waits) ----
        bf16x8 bfr[4][2];
        #pragma unroll
        for (int ni = 0; ni < 4; ni++)
            #pragma unroll
            for (int kh = 0; kh < 2; kh++)
                bfr[ni][kh] = *(const bf16x8*)(bbase + (size_t)(ni * 16) * 832 + k0 + kh * 32);

        // ---- A frags from LDS slot buf ----
        const uint16_t* Ac = Als + buf * 2304;
        bf16x8 afr[2][2];
        #pragma unroll
        for (int mi = 0; mi < 2; mi++)
            #pragma unroll
            for (int kh = 0; kh < 2; kh++)
                afr[mi][kh] = *(const bf16x8*)&Ac[(mi * 16 + lm) * 72 + kh * 32 + lq * 8];

        // ---- stage tile it+1 -> other slot; issue loads for tile it+2 ----
        if (it + 1 < 13) {
            *(bf16x8*)&Als[(buf ^ 1) * 2304 + swaddr] = pack8(q0, q1);
            if (it + 2 < 13) {
                int kn = (it + 2) * 64;
                int c = kn + sc_;
                if (c < 784) {
                    q0 = *(const float4*)(xrow + kn);
                    q1 = *(const float4*)(xrow + kn + 4);
                } else {
                    q0 = q1 = make_float4(0.f, 0.f, 0.f, 0.f);
                }
            }
        }

        // ---- 16 MFMA ----
        #pragma unroll
        for (int kh = 0; kh < 2; kh++)
            #pragma unroll
            for (int ni = 0; ni < 4; ni++) {
                acc[0][ni] = mfma16x16x32(afr[0][kh], bfr[ni][kh], acc[0][ni]);
                acc[1][ni] = mfma16x16x32(afr[1][kh], bfr[ni][kh], acc[1][ni]);
            }

        lds_barrier();   // lgkm-only; A dbuf rotate
        buf ^= 1;
    }

    // ---- GEMM1 epilogue: relu(+bias) -> Htile bf16 [32][272] ----
    #pragma unroll
    for (int ni = 0; ni < 4; ni++) {
        int n = w * 64 + ni * 16 + lm;
        float bias = be1[n];
        #pragma unroll
        for (int mi = 0; mi < 2; mi++) {
            #pragma unroll
            for (int i = 0; i < 4; i++) {
                int r = mi * 16 + lq * 4 + i;
                float v = acc[mi][ni][i] + bias;
                v = v > 0.f ? v : 0.f;
                Htile[r * 272 + n] = f2bf(v);
            }
        }
    }
    __syncthreads();   // Htile complete

    // ---- GEMM2: enc_pre = h @ We2, K=256. wave w -> rows (w&1)*16, cols (w>>1)*16 ----
    const int mrow = (w & 1) * 16;
    const int ncol = (w >> 1) * 16;
    f32x4 acc2 = {};
    #pragma unroll
    for (int k0 = 0; k0 < 256; k0 += 32) {
        bf16x8 af = *(const bf16x8*)&Htile[(mrow + lm) * 272 + k0 + lq * 8];
        bf16x8 bf = *(const bf16x8*)&We2T[(ncol + lm) * 256 + k0 + lq * 8];
        acc2 = mfma16x16x32(af, bf, acc2);
    }
    __syncthreads();   // all Htile reads done; arena becomes enc/feat/a1

    // ---- enc = tanh(acc + be2) -> LDS ----
    {
        int col = ncol + lm;
        float bias = be2[col];
        #pragma unroll
        for (int i = 0; i < 4; i++) {
            int r = mrow + lq * 4 + i;
            encls[r * 33 + col] = tanhf(acc2[i] + bias);
        }
    }
    __syncthreads();   // enc visible cross-wave

    // ---- per-row: normalize + quantum circuit -> feat bf16 ----
    if (t < 32) {
        float e[32];
        #pragma unroll
        for (int j = 0; j < 32; j++) e[j] = encls[t * 33 + j];
        float s = 0.f;
        #pragma unroll
        for (int j = 0; j < 32; j++) s += e[j] * e[j];
        float inv = 1.0f / sqrtf(s);
        float sr[16], si[16];
        #pragma unroll
        for (int i = 0; i < 16; i++) { sr[i] = e[i] * inv; si[i] = e[16 + i] * inv; }
        circuit(sr, si);
        #pragma unroll
        for (int i = 0; i < 16; i++) {
            featls[t * 40 + i]      = f2bf(sr[i]);
            featls[t * 40 + 16 + i] = f2bf(si[i]);
        }
    }
    __syncthreads();   // feat visible cross-wave

    // ---- classifier L1: a1 = relu(feat @ W1 + b1), K=32. wave w -> rows (w&1)*16, cols (w>>1)*64 ----
    const int nc64 = (w >> 1) * 64;
    f32x4 acc3[4] = {};
    {
        bf16x8 af = *(const bf16x8*)&featls[(mrow + lm) * 40 + lq * 8];
        #pragma unroll
        for (int ni = 0; ni < 4; ni++) {
            bf16x8 bf = *(const bf16x8*)&W1T[(nc64 + ni * 16 + lm) * 32 + lq * 8];
            acc3[ni] = mfma16x16x32(af, bf, acc3[ni]);
        }
    }
    #pragma unroll
    for (int ni = 0; ni < 4; ni++) {
        int col = nc64 + ni * 16 + lm;
        float bias = b1[col];
        #pragma unroll
        for (int i = 0; i < 4; i++) {
            int r = mrow + lq * 4 + i;
            float v = acc3[ni][i] + bias;
            v = v > 0.f ? v : 0.f;
            a1ls[r * 136 + col] = f2bf(v);
        }
    }
    __syncthreads();   // cross-wave: L2 reads cols written by other waves

    // ---- classifier L2: out = a1 @ W2 + b2, K=128, N=16 (10 real). waves 0,1 only ----
    if (w < 2) {
        f32x4 acc4 = {};
        #pragma unroll
        for (int k0 = 0; k0 < 128; k0 += 32) {
            bf16x8 af = *(const bf16x8*)&a1ls[(w * 16 + lm) * 136 + k0 + lq * 8];
            bf16x8 bf = *(const bf16x8*)&W2T[lm * 128 + k0 + lq * 8];
            acc4 = mfma16x16x32(af, bf, acc4);
        }
        if (lm < 10) {
            float bias = b2[lm];
            #pragma unroll
            for (int i = 0; i < 4; i++) {
                int r = rowbase + w * 16 + lq * 4 + i;
                out[(size_t)r * 10 + lm] = acc4[i] + bias;
            }
        }
    }
}

extern "C" void kernel_launch(void* const* d_in, const int* in_sizes, int n_in,
                              void* d_out, int out_size, void* d_ws, size_t ws_size,
                              hipStream_t stream) {
    const float* x   = (const float*)d_in[0];
    const float* We1 = (const float*)d_in[1];
    const float* be1 = (const float*)d_in[2];
    const float* We2 = (const float*)d_in[3];
    const float* be2 = (const float*)d_in[4];
    const float* W1  = (const float*)d_in[5];
    const float* b1  = (const float*)d_in[6];
    const float* W2  = (const float*)d_in[7];
    const float* b2  = (const float*)d_in[8];
    float* out = (float*)d_out;

    char* ws = (char*)d_ws;
    uint16_t* We1T = (uint16_t*)(ws + WS_WE1T);
    uint16_t* We2T = (uint16_t*)(ws + WS_WE2T);
    uint16_t* W1T  = (uint16_t*)(ws + WS_W1T);
    uint16_t* W2T  = (uint16_t*)(ws + WS_W2T);

    hipLaunchKernelGGL(prep_weights, dim3(888), dim3(256), 0, stream,
                       We1, We2, W1, W2, We1T, We2T, W1T, W2T);
    hipLaunchKernelGGL(fused_kernel, dim3(2048), dim3(256), 0, stream,
                       x, We1T, be1, We2T, be2, W1T, b1, W2T, b2, out);
}